// Round 9
// baseline (1890.340 us; speedup 1.0000x reference)
//
#include <hip/hip_runtime.h>
#include <math.h>

// LSTM: B=64, T=2048, I=200, H=100. Output h_T [64,100] fp32.
// FUSED persistent producer/consumer kernel, 256 blocks x 256 thr (1/CU):
//   - blocks 0..63   : LSTM recurrence, 4 waves (1/SIMD), HALF-split:
//                      thread (q=tid>>1, s2=tid&1) owns all 4 gates of unit q
//                      over half of h (56 elems, 112 pk_fma). One-stage
//                      transposed pair reduce (lane s2 finishes gates s2,s2+2),
//                      2 activations/thread, 2-DPP redistribution.
//                      4-wave barrier (was 8), full SIMD issue ownership.
//   - blocks 64..255 : 192 producer blocks computing xproj one chunk ahead
//                      (R5 xproj geometry at 256 thr: 64-t-row x 128-gate jobs).
//   Sync: device-scope atomics on done[]/freed[] + __threadfence().
//   R5-R8 fixes retained: unconditional clamped depth-4 xg prefetch,
//   LDS-only barrier (lgkmcnt drain, vmcnt stays in flight), own-gate act.

#define T_TOTAL 2048
#define B_SZ 64
#define IN_SZ 200
#define H_SZ 100
#define GP 512   // padded gate dim (4*H=400 -> 512)
#define KP 112   // padded hidden dim for Whh rows (100 -> 112, half = 56)
#define NPROD 192
#define NBLK 256

typedef float v2f __attribute__((ext_vector_type(2)));

__device__ __forceinline__ float sigf(float x) {
    return __builtin_amdgcn_rcpf(1.f + __expf(-x));
}

// quad_perm DPP move (bound_ctrl=true); 0xB1 = [1,0,3,2] pair swap
#define QSWAP(x, ctrl) \
    __int_as_float(__builtin_amdgcn_mov_dpp(__float_as_int(x), ctrl, 0xF, 0xF, true))

// LDS-only barrier: ds ops drained, global loads stay in flight.
#define LDS_BARRIER()                                          \
    do {                                                       \
        asm volatile("s_waitcnt lgkmcnt(0)" ::: "memory");     \
        __builtin_amdgcn_s_barrier();                          \
    } while (0)

// ---------------- prep ----------------
__global__ void prep_kernel(const float* __restrict__ W_ih,
                            const float* __restrict__ W_hh,
                            const float* __restrict__ b_ih,
                            const float* __restrict__ b_hh,
                            float* __restrict__ Wt,
                            float* __restrict__ bias,
                            float* __restrict__ Whp,
                            unsigned int* __restrict__ sync) {
    int idx = blockIdx.x * 256 + threadIdx.x;
    if (idx < IN_SZ * GP) {
        int k = idx >> 9;
        int g = idx & (GP - 1);
        Wt[idx] = (g < 400) ? W_ih[g * IN_SZ + k] : 0.f;
    }
    if (idx < GP) bias[idx] = (idx < 400) ? (b_ih[idx] + b_hh[idx]) : 0.f;
    if (idx < 400 * KP) {
        int g = idx / KP;
        int k = idx - g * KP;
        Whp[idx] = (k < H_SZ) ? W_hh[g * H_SZ + k] : 0.f;
    }
    if (idx < 64) sync[idx] = 0u;  // done[0..31], freed[0..31]
}

// ---------------- fused persistent kernel ----------------
__global__ __attribute__((amdgpu_flat_work_group_size(256, 256), amdgpu_waves_per_eu(1, 1)))
void fused_kernel(const float* __restrict__ x,
                  const float* __restrict__ Wt,
                  const float* __restrict__ bias,
                  const float* __restrict__ Whp,
                  float* __restrict__ xg,   // NB ring slots, + 8KB slack after
                  float* __restrict__ out,
                  unsigned int* __restrict__ sync,
                  int TC, int NB, int nch) {
    __shared__ __align__(16) float hlds[2][KP];       // consumer (896 B)
    __shared__ __align__(16) float xTc[50][68];       // producer (13.6 KB)
    __shared__ __align__(16) float4 LW[50][32];       // producer (25.6 KB)

    const int bid = blockIdx.x;
    const int tid = threadIdx.x;
    unsigned int* done = sync;
    unsigned int* freed = sync + 32;
    const size_t slot_sz = (size_t)B_SZ * TC * GP;

    if (bid < B_SZ) {
        // ================= consumer: LSTM recurrence =================
        const int b = bid;
        const int q = tid >> 1;
        const int s2 = tid & 1;
        const bool active = (q < H_SZ);
        const int qc = active ? q : (H_SZ - 1);
        // slot-b activation: lane s2==0 holds gate 2 (tanh), s2==1 gate 3 (sigmoid)
        const float bsc  = (s2 == 0) ? 2.f : 1.f;
        const float bmul = (s2 == 0) ? 2.f : 1.f;
        const float badd = (s2 == 0) ? -1.f : 0.f;

        // 4 gate half-rows: 4 x 28 v2f = 224 regs (unified VGPR/AGPR file).
        v2f w[4][28];
        if (active) {
            const v2f* W2 = (const v2f*)Whp;
#pragma unroll
            for (int g = 0; g < 4; ++g) {
                const v2f* row = W2 + (size_t)(g * H_SZ + q) * (KP / 2) + s2 * 28;
#pragma unroll
                for (int m = 0; m < 28; ++m) w[g][m] = row[m];
            }
        } else {
#pragma unroll
            for (int g = 0; g < 4; ++g)
#pragma unroll
                for (int m = 0; m < 28; ++m) { w[g][m].x = 0.f; w[g][m].y = 0.f; }
        }

        float c = 0.f;
        if (tid < KP) hlds[0][tid] = 0.f;
        if (tid < KP - H_SZ) hlds[1][H_SZ + tid] = 0.f;  // zero pad of buffer 1
        __syncthreads();

        // per-thread xg pointer: gate a = s2*100+qc; gate b = +200 floats
        const size_t lane_off = (size_t)(s2 * H_SZ + qc);
        float hval = 0.f;

        // One LSTM step, half-split. Transposed PAIR reduce (1 DPP stage):
        //   p[g] = partial dot of gate g over half s2.
        //   ra: lane0 = full g0, lane1 = full g1; rb: lane0 = g2, lane1 = g3.
        //   Lane activates its 2 gates (a: sigmoid; b: tanh on lane0),
        //   1 pair-swap each redistributes -> i,f,g,o on both lanes.
#define LSTM_STEP(XA, XB, RB, WB, KOFF)                                        \
    {                                                                          \
        const float4* hb4 = (const float4*)&hlds[RB][s2 * 56];                 \
        float4 h4 = hb4[0];                                                    \
        v2f hlo; hlo.x = h4.x; hlo.y = h4.y;                                   \
        v2f hhi; hhi.x = h4.z; hhi.y = h4.w;                                   \
        v2f a0[4], a1[4];                                                      \
        _Pragma("unroll") for (int g = 0; g < 4; ++g) {                        \
            a0[g] = hlo * w[g][0];                                             \
            a1[g] = hhi * w[g][1];                                             \
        }                                                                      \
        _Pragma("unroll") for (int m = 1; m < 14; ++m) {                       \
            h4 = hb4[m];                                                       \
            hlo.x = h4.x; hlo.y = h4.y;                                        \
            hhi.x = h4.z; hhi.y = h4.w;                                        \
            _Pragma("unroll") for (int g = 0; g < 4; ++g) {                    \
                a0[g] = __builtin_elementwise_fma(hlo, w[g][2 * m], a0[g]);    \
                a1[g] = __builtin_elementwise_fma(hhi, w[g][2 * m + 1], a1[g]);\
            }                                                                  \
        }                                                                      \
        float p[4];                                                            \
        _Pragma("unroll") for (int g = 0; g < 4; ++g) {                        \
            v2f sv = a0[g] + a1[g];                                            \
            p[g] = sv.x + sv.y;                                                \
        }                                                                      \
        float ea = s2 ? p[0] : p[1];                                           \
        float ra = (s2 ? p[1] : p[0]) + QSWAP(ea, 0xB1);                       \
        float eb = s2 ? p[2] : p[3];                                           \
        float rb = (s2 ? p[3] : p[2]) + QSWAP(eb, 0xB1);                       \
        float dwa = ra + XA;                                                   \
        float dwb = rb + XB;                                                   \
        XA = xq[(KOFF) * GP];                                                  \
        XB = xq[(KOFF) * GP + 2 * H_SZ];                                       \
        float acta = sigf(dwa);                                                \
        float actb = __builtin_fmaf(sigf(bsc * dwb), bmul, badd);              \
        float fa = QSWAP(acta, 0xB1);                                          \
        float fb = QSWAP(actb, 0xB1);                                          \
        float vi = s2 ? fa : acta;                                             \
        float vf = s2 ? acta : fa;                                             \
        float vg = s2 ? fb : actb;                                             \
        float vo = s2 ? actb : fb;                                             \
        c = __builtin_fmaf(vf, c, vi * vg);                                    \
        float tcv = __builtin_fmaf(sigf(2.f * c), 2.f, -1.f);                  \
        hval = vo * tcv;                                                       \
        if (active && s2 == 0) hlds[WB][q] = hval;                             \
        LDS_BARRIER();                                                         \
    }

        for (int k = 0; k < nch; ++k) {
            if (tid == 0) {
                while (atomicAdd(&done[k], 0u) < (unsigned)NPROD)
                    __builtin_amdgcn_s_sleep(8);
                __threadfence();  // acquire
            }
            __syncthreads();  // full drain once per chunk

            const float* xp = xg + (size_t)(k % NB) * slot_sz + (size_t)b * TC * GP + lane_off;
            float xa0 = xp[0 * GP], xb0 = xp[0 * GP + 2 * H_SZ];
            float xa1 = xp[1 * GP], xb1 = xp[1 * GP + 2 * H_SZ];
            float xa2 = xp[2 * GP], xb2 = xp[2 * GP + 2 * H_SZ];
            float xa3 = xp[3 * GP], xb3 = xp[3 * GP + 2 * H_SZ];
            const float* xq = xp + 4 * GP;

            for (int tl = 0; tl < TC; tl += 4) {
                LSTM_STEP(xa0, xb0, 0, 1, 0);
                LSTM_STEP(xa1, xb1, 1, 0, 1);
                LSTM_STEP(xa2, xb2, 0, 1, 2);
                LSTM_STEP(xa3, xb3, 1, 0, 3);
                xq += 4 * GP;
            }
            if (tid == 0) atomicAdd(&freed[k], 1u);
        }
#undef LSTM_STEP

        if (active && s2 == 0) out[b * H_SZ + q] = hval;

    } else {
        // ================= producer: xproj, one chunk ahead =================
        // R5 xproj geometry at 256 thr: job = (batch, 64-t-row tile, gblk).
        const int pid = bid - B_SZ;     // 0..191
        const int gt = tid & 15;
        const int tt = tid >> 4;        // 0..15
        const int TPB = TC >> 6;        // 64-row tiles per batch per chunk
        const int njobs = B_SZ * TPB * 4;
        const float2* x2 = (const float2*)x;
        const float4* Wt4 = (const float4*)Wt;
        const float4* bias4 = (const float4*)bias;

        for (int k = 0; k < nch; ++k) {
            if (k >= NB) {
                if (tid == 0)
                    while (atomicAdd(&freed[k - NB], 0u) < (unsigned)B_SZ)
                        __builtin_amdgcn_s_sleep(8);
                __syncthreads();
            }
            float* slot = xg + (size_t)(k % NB) * slot_sz;
            float4* slot4 = (float4*)slot;

            for (int job = pid; job < njobs; job += NPROD) {
                const int b = job / (TPB * 4);
                const int r = job - b * (TPB * 4);
                const int tj = r >> 2;
                const int gblk = r & 3;
                const int tl0 = tj * 64;                 // local t base
                const int ta0 = k * TC + tl0;            // absolute t base

                v2f acc[4][4];
#pragma unroll
                for (int tr = 0; tr < 4; ++tr)
#pragma unroll
                    for (int hh = 0; hh < 4; ++hh) { acc[tr][hh].x = 0.f; acc[tr][hh].y = 0.f; }

                for (int kc = 0; kc < 4; ++kc) {
                    for (int idx = tid; idx < 64 * 25; idx += 256) {
                        int row = idx / 25, c2 = idx % 25;
                        float2 v = x2[(size_t)(b * T_TOTAL + ta0 + row) * (IN_SZ / 2) + kc * 25 + c2];
                        xTc[c2 * 2][row] = v.x;
                        xTc[c2 * 2 + 1][row] = v.y;
                    }
                    for (int idx = tid; idx < 50 * 32; idx += 256) {
                        int kk = idx >> 5, cc = idx & 31;
                        LW[kk][cc] = Wt4[(size_t)(kc * 50 + kk) * (GP / 4) + gblk * 32 + cc];
                    }
                    __syncthreads();

#pragma unroll 5
                    for (int kk = 0; kk < 50; ++kk) {
                        float4 xv = *(const float4*)&xTc[kk][tt * 4];
                        float4 w0 = LW[kk][gt];
                        float4 w1 = LW[kk][16 + gt];
                        v2f wv[4];
                        wv[0].x = w0.x; wv[0].y = w0.y; wv[1].x = w0.z; wv[1].y = w0.w;
                        wv[2].x = w1.x; wv[2].y = w1.y; wv[3].x = w1.z; wv[3].y = w1.w;
                        float xa[4] = {xv.x, xv.y, xv.z, xv.w};
#pragma unroll
                        for (int tr = 0; tr < 4; ++tr) {
                            v2f xs; xs.x = xa[tr]; xs.y = xa[tr];
#pragma unroll
                            for (int hh = 0; hh < 4; ++hh)
                                acc[tr][hh] = __builtin_elementwise_fma(xs, wv[hh], acc[tr][hh]);
                        }
                    }
                    __syncthreads();
                }

                float4 b0 = bias4[gblk * 32 + gt];
                float4 b1 = bias4[gblk * 32 + 16 + gt];
#pragma unroll
                for (int tr = 0; tr < 4; ++tr) {
                    int trow = tl0 + tt * 4 + tr;
                    size_t o = (size_t)(b * TC + trow) * (GP / 4) + gblk * 32;
                    float4 v0 = make_float4(acc[tr][0].x + b0.x, acc[tr][0].y + b0.y,
                                            acc[tr][1].x + b0.z, acc[tr][1].y + b0.w);
                    float4 v1 = make_float4(acc[tr][2].x + b1.x, acc[tr][2].y + b1.y,
                                            acc[tr][3].x + b1.z, acc[tr][3].y + b1.w);
                    slot4[o + gt] = v0;
                    slot4[o + 16 + gt] = v1;
                }
            }
            __syncthreads();  // drains all waves' stores before signal
            if (tid == 0) {
                __threadfence();         // release
                atomicAdd(&done[k], 1u);
            }
        }
    }
}

// ---------------- host ----------------
extern "C" void kernel_launch(void* const* d_in, const int* in_sizes, int n_in,
                              void* d_out, int out_size, void* d_ws, size_t ws_size,
                              hipStream_t stream) {
    const float* x    = (const float*)d_in[0];
    const float* W_ih = (const float*)d_in[1];
    const float* W_hh = (const float*)d_in[2];
    const float* b_ih = (const float*)d_in[3];
    const float* b_hh = (const float*)d_in[4];
    float* out = (float*)d_out;

    char* ws = (char*)d_ws;
    float* Wt           = (float*)(ws);            // 200*512*4  = 409600
    float* bias         = (float*)(ws + 409600);   // 512*4      = 2048
    float* Whp          = (float*)(ws + 411648);   // 400*112*4  = 179200 -> 590848
    unsigned int* sync  = (unsigned int*)(ws + 590848);  // 64*4 = 256 -> 591104
    float* xgbuf        = (float*)(ws + 593920);   // ring buffers + 8KB slack

    size_t avail = (ws_size > 593920 + 8192) ? (ws_size - 593920 - 8192) : 0;
    int TC, NB;
    if (avail >= 2ull * B_SZ * 256 * GP * 4)      { TC = 256; NB = 2; }
    else if (avail >= 2ull * B_SZ * 128 * GP * 4) { TC = 128; NB = 2; }
    else                                          { TC = 128; NB = 1; }
    int nch = T_TOTAL / TC;

    prep_kernel<<<400, 256, 0, stream>>>(W_ih, W_hh, b_ih, b_hh, Wt, bias, Whp, sync);
    fused_kernel<<<NBLK, 256, 0, stream>>>(x, Wt, bias, Whp, xgbuf, out, sync,
                                           TC, NB, nch);
}

// Round 10
// 1242.297 us; speedup vs baseline: 1.5216x; 1.5216x over previous
//
#include <hip/hip_runtime.h>
#include <math.h>

// LSTM: B=64, T=2048, I=200, H=100. Output h_T [64,100] fp32.
// FUSED persistent producer/consumer kernel (512 thr, R8 structure):
//   - blocks 0..63   : LSTM recurrence (quarter-split, transposed quad reduce,
//                      own-gate activation, LDS-only per-step barrier).
//   - blocks 64..255 : 192 producer blocks computing xproj one chunk ahead.
//   Sync: device-scope atomics on done[]/freed[] + __threadfence().
// ROUND 10 change: xg layout TRANSPOSED to [b][gate][t].
//   Theory: consumer step was xg SUPPLY-RATE bound -- depth-4 scalar pipeline
//   with ~600-900 cyc cross-XCD load latency sustains >= L/4 ~ 200 cyc/step.
//   Now each thread loads ONE float4 (4 steps of its gate's x, t-contiguous)
//   per 4 steps, 4 quads in flight, time loop unrolled x16: issue-to-consume
//   distance ~13 steps -> supply bound ~L/13, and 4x fewer load instructions.
//   Producer epilogue writes 8 t-contiguous float4s (same bytes, same math).
// (R9 lesson: 256-thr blocks halved producer capacity -> starvation. Reverted.)

#define T_TOTAL 2048
#define B_SZ 64
#define IN_SZ 200
#define H_SZ 100
#define GP 512   // padded gate dim (4*H=400 -> 512)
#define KP 112   // padded hidden dim for Whh rows (100 -> 112, quarter = 28)
#define NPROD 192
#define NBLK 256

typedef float v2f __attribute__((ext_vector_type(2)));

__device__ __forceinline__ float sigf(float x) {
    return __builtin_amdgcn_rcpf(1.f + __expf(-x));
}

// quad_perm DPP move (bound_ctrl=true)
#define QSWAP(x, ctrl) \
    __int_as_float(__builtin_amdgcn_mov_dpp(__float_as_int(x), ctrl, 0xF, 0xF, true))
// broadcast lane (ctrl) of each quad to all 4 lanes
#define QBCAST(x, ctrl) QSWAP(x, ctrl)

// LDS-only barrier: ds ops drained, global loads stay in flight.
#define LDS_BARRIER()                                          \
    do {                                                       \
        asm volatile("s_waitcnt lgkmcnt(0)" ::: "memory");     \
        __builtin_amdgcn_s_barrier();                          \
    } while (0)

// ---------------- prep ----------------
__global__ void prep_kernel(const float* __restrict__ W_ih,
                            const float* __restrict__ W_hh,
                            const float* __restrict__ b_ih,
                            const float* __restrict__ b_hh,
                            float* __restrict__ Wt,
                            float* __restrict__ bias,
                            float* __restrict__ Whp,
                            unsigned int* __restrict__ sync) {
    int idx = blockIdx.x * 256 + threadIdx.x;
    if (idx < IN_SZ * GP) {
        int k = idx >> 9;
        int g = idx & (GP - 1);
        Wt[idx] = (g < 400) ? W_ih[g * IN_SZ + k] : 0.f;
    }
    if (idx < GP) bias[idx] = (idx < 400) ? (b_ih[idx] + b_hh[idx]) : 0.f;
    if (idx < 400 * KP) {
        int g = idx / KP;
        int k = idx - g * KP;
        Whp[idx] = (k < H_SZ) ? W_hh[g * H_SZ + k] : 0.f;
    }
    if (idx < 64) sync[idx] = 0u;  // done[0..31], freed[0..31]
}

// ---------------- fused persistent kernel ----------------
__global__ __attribute__((amdgpu_flat_work_group_size(512, 512), amdgpu_waves_per_eu(2, 2)))
void fused_kernel(const float* __restrict__ x,
                  const float* __restrict__ Wt,
                  const float* __restrict__ bias,
                  const float* __restrict__ Whp,
                  float* __restrict__ xg,   // NB ring slots, layout [b][gate][t]
                  float* __restrict__ out,
                  unsigned int* __restrict__ sync,
                  int TC, int NB, int nch) {
    __shared__ __align__(16) float hlds[2][KP];       // consumer
    __shared__ __align__(16) float xTc[2][50][68];    // producer
    __shared__ __align__(16) float4 LW[50][32];       // producer

    const int bid = blockIdx.x;
    const int tid = threadIdx.x;
    unsigned int* done = sync;
    unsigned int* freed = sync + 32;
    const size_t slot_sz = (size_t)B_SZ * TC * GP;

    if (bid < B_SZ) {
        // ================= consumer: LSTM recurrence =================
        const int b = bid;
        const int q = tid >> 2;
        const int s4 = tid & 3;
        const bool active = (q < H_SZ);
        const int qc = active ? q : (H_SZ - 1);
        const bool o1 = (s4 & 1) != 0;
        const bool o2 = (s4 & 2) != 0;
        // own-gate activation constants: s4==2 is the tanh gate (g)
        const float asc  = (s4 == 2) ? 2.f : 1.f;
        const float amul = (s4 == 2) ? 2.f : 1.f;
        const float aadd = (s4 == 2) ? -1.f : 0.f;

        v2f w[4][14];
        if (active) {
            const v2f* W2 = (const v2f*)Whp;
#pragma unroll
            for (int g = 0; g < 4; ++g) {
                const v2f* row = W2 + (size_t)(g * H_SZ + q) * (KP / 2) + s4 * 14;
#pragma unroll
                for (int m = 0; m < 14; ++m) w[g][m] = row[m];
            }
        } else {
#pragma unroll
            for (int g = 0; g < 4; ++g)
#pragma unroll
                for (int m = 0; m < 14; ++m) { w[g][m].x = 0.f; w[g][m].y = 0.f; }
        }

        float c = 0.f;
        if (tid < KP) hlds[0][tid] = 0.f;
        if (tid < KP - H_SZ) hlds[1][H_SZ + tid] = 0.f;
        __syncthreads();

        const int gate = s4 * H_SZ + qc;  // this lane's gate row in xg[b][gate][t]
        float hval = 0.f;

        // One LSTM step. XV = this step's xg value (component of an in-flight
        // float4 quad). Transposed quad reduce -> lane s4 holds only gate s4's
        // dot; activates it; 4 quad-broadcasts redistribute i,f,g,o.
#define LSTM_STEP(XV, RB, WB)                                                  \
    {                                                                          \
        const float4* hb4 = (const float4*)&hlds[RB][s4 * 28];                 \
        float4 h4 = hb4[0];                                                    \
        v2f hlo; hlo.x = h4.x; hlo.y = h4.y;                                   \
        v2f hhi; hhi.x = h4.z; hhi.y = h4.w;                                   \
        v2f a0[4], a1[4];                                                      \
        _Pragma("unroll") for (int g = 0; g < 4; ++g) {                        \
            a0[g] = hlo * w[g][0];                                             \
            a1[g] = hhi * w[g][1];                                             \
        }                                                                      \
        _Pragma("unroll") for (int m = 1; m < 7; ++m) {                        \
            h4 = hb4[m];                                                       \
            hlo.x = h4.x; hlo.y = h4.y;                                        \
            hhi.x = h4.z; hhi.y = h4.w;                                        \
            _Pragma("unroll") for (int g = 0; g < 4; ++g) {                    \
                a0[g] = __builtin_elementwise_fma(hlo, w[g][2 * m], a0[g]);    \
                a1[g] = __builtin_elementwise_fma(hhi, w[g][2 * m + 1], a1[g]);\
            }                                                                  \
        }                                                                      \
        float p[4];                                                            \
        _Pragma("unroll") for (int g = 0; g < 4; ++g) {                        \
            v2f sv = a0[g] + a1[g];                                            \
            p[g] = sv.x + sv.y;                                                \
        }                                                                      \
        float e01 = o1 ? p[0] : p[1];                                          \
        float r01 = (o1 ? p[1] : p[0]) + QSWAP(e01, 0xB1);                     \
        float e23 = o1 ? p[2] : p[3];                                          \
        float r23 = (o1 ? p[3] : p[2]) + QSWAP(e23, 0xB1);                     \
        float ecx = o2 ? r01 : r23;                                            \
        float dwn = (o2 ? r23 : r01) + QSWAP(ecx, 0x4E) + (XV);                \
        float act = __builtin_fmaf(sigf(asc * dwn), amul, aadd);               \
        float vi = QBCAST(act, 0x00);                                          \
        float vf = QBCAST(act, 0x55);                                          \
        float vg = QBCAST(act, 0xAA);                                          \
        float vo = QBCAST(act, 0xFF);                                          \
        c = __builtin_fmaf(vf, c, vi * vg);                                    \
        float tcv = __builtin_fmaf(sigf(2.f * c), 2.f, -1.f);                  \
        hval = vo * tcv;                                                       \
        if (active && s4 == 0) hlds[WB][q] = hval;                             \
        LDS_BARRIER();                                                         \
    }

        for (int k = 0; k < nch; ++k) {
            if (tid == 0) {
                while (atomicAdd(&done[k], 0u) < (unsigned)NPROD)
                    __builtin_amdgcn_s_sleep(8);
                __threadfence();  // acquire
            }
            __syncthreads();  // full drain once per chunk

            // this lane's gate row, t-contiguous
            const float4* xr = (const float4*)(xg + (size_t)(k % NB) * slot_sz
                                               + ((size_t)b * GP + gate) * TC);
            float4 X0 = xr[0];   // steps 0..3
            float4 X1 = xr[1];   // steps 4..7
            float4 X2 = xr[2];   // steps 8..11
            float4 X3 = xr[3];   // steps 12..15
            const float4* xq4 = xr + 4;  // reload cursor (t+16 for group 0)

            for (int tl = 0; tl < TC; tl += 16) {
                LSTM_STEP(X0.x, 0, 1); LSTM_STEP(X0.y, 1, 0);
                LSTM_STEP(X0.z, 0, 1); LSTM_STEP(X0.w, 1, 0);
                X0 = xq4[0];  // steps t+16..t+19 (last group: discarded overread, in-slot)
                LSTM_STEP(X1.x, 0, 1); LSTM_STEP(X1.y, 1, 0);
                LSTM_STEP(X1.z, 0, 1); LSTM_STEP(X1.w, 1, 0);
                X1 = xq4[1];
                LSTM_STEP(X2.x, 0, 1); LSTM_STEP(X2.y, 1, 0);
                LSTM_STEP(X2.z, 0, 1); LSTM_STEP(X2.w, 1, 0);
                X2 = xq4[2];
                LSTM_STEP(X3.x, 0, 1); LSTM_STEP(X3.y, 1, 0);
                LSTM_STEP(X3.z, 0, 1); LSTM_STEP(X3.w, 1, 0);
                X3 = xq4[3];
                xq4 += 4;
            }
            if (tid == 0) atomicAdd(&freed[k], 1u);
        }
#undef LSTM_STEP

        if (active && s4 == 0) out[b * H_SZ + q] = hval;

    } else {
        // ================= producer: xproj, one chunk ahead =================
        const int pid = bid - B_SZ;     // 0..191
        const int h = tid >> 8;         // half: rows [h*64, h*64+64)
        const int t2 = tid & 255;
        const int gt = t2 & 15;
        const int tt = t2 >> 4;
        const int TPB = TC >> 7;        // 128-row tiles per batch per chunk
        const int njobs = B_SZ * TPB * 4;
        const float2* x2 = (const float2*)x;
        const float4* Wt4 = (const float4*)Wt;
        const float4* bias4 = (const float4*)bias;

        for (int k = 0; k < nch; ++k) {
            if (k >= NB) {
                if (tid == 0)
                    while (atomicAdd(&freed[k - NB], 0u) < (unsigned)B_SZ)
                        __builtin_amdgcn_s_sleep(8);
                __syncthreads();
            }
            float* slot = xg + (size_t)(k % NB) * slot_sz;

            for (int job = pid; job < njobs; job += NPROD) {
                const int b = job / (TPB * 4);
                const int r = job - b * (TPB * 4);
                const int tj = r >> 2;
                const int gblk = r & 3;
                const int tl0 = tj * 128 + h * 64;       // local t base (this half)
                const int ta0 = k * TC + tl0;            // absolute t base

                v2f acc[4][4];
#pragma unroll
                for (int tr = 0; tr < 4; ++tr)
#pragma unroll
                    for (int hh = 0; hh < 4; ++hh) { acc[tr][hh].x = 0.f; acc[tr][hh].y = 0.f; }

                for (int kc = 0; kc < 4; ++kc) {
                    for (int idx = t2; idx < 64 * 25; idx += 256) {
                        int row = idx / 25, c2 = idx % 25;
                        float2 v = x2[(size_t)(b * T_TOTAL + ta0 + row) * (IN_SZ / 2) + kc * 25 + c2];
                        xTc[h][c2 * 2][row] = v.x;
                        xTc[h][c2 * 2 + 1][row] = v.y;
                    }
                    for (int idx = tid; idx < 50 * 32; idx += 512) {
                        int kk = idx >> 5, cc = idx & 31;
                        LW[kk][cc] = Wt4[(size_t)(kc * 50 + kk) * (GP / 4) + gblk * 32 + cc];
                    }
                    __syncthreads();

#pragma unroll 5
                    for (int kk = 0; kk < 50; ++kk) {
                        float4 xv = *(const float4*)&xTc[h][kk][tt * 4];
                        float4 w0 = LW[kk][gt];
                        float4 w1 = LW[kk][16 + gt];
                        v2f wv[4];
                        wv[0].x = w0.x; wv[0].y = w0.y; wv[1].x = w0.z; wv[1].y = w0.w;
                        wv[2].x = w1.x; wv[2].y = w1.y; wv[3].x = w1.z; wv[3].y = w1.w;
                        float xa[4] = {xv.x, xv.y, xv.z, xv.w};
#pragma unroll
                        for (int tr = 0; tr < 4; ++tr) {
                            v2f xs; xs.x = xa[tr]; xs.y = xa[tr];
#pragma unroll
                            for (int hh = 0; hh < 4; ++hh)
                                acc[tr][hh] = __builtin_elementwise_fma(xs, wv[hh], acc[tr][hh]);
                        }
                    }
                    __syncthreads();
                }

                // transposed epilogue: xg[b][gate][t], t contiguous.
                // This thread holds times t0l..t0l+3 for gates
                //   (gblk*32+gt)*4+j and (gblk*32+16+gt)*4+j, j=0..3.
                const int t0l = tl0 + tt * 4;
                float4 b0 = bias4[gblk * 32 + gt];
                float4 b1 = bias4[gblk * 32 + 16 + gt];
                float bb0[4] = {b0.x, b0.y, b0.z, b0.w};
                float bb1[4] = {b1.x, b1.y, b1.z, b1.w};
                const size_t base0 = ((size_t)b * GP + (size_t)((gblk * 32 + gt) * 4)) * TC + t0l;
                const size_t base1 = ((size_t)b * GP + (size_t)((gblk * 32 + 16 + gt) * 4)) * TC + t0l;
#pragma unroll
                for (int j = 0; j < 4; ++j) {
                    float4 v0 = make_float4(acc[0][j >> 1][j & 1] + bb0[j],
                                            acc[1][j >> 1][j & 1] + bb0[j],
                                            acc[2][j >> 1][j & 1] + bb0[j],
                                            acc[3][j >> 1][j & 1] + bb0[j]);
                    float4 v1 = make_float4(acc[0][2 + (j >> 1)][j & 1] + bb1[j],
                                            acc[1][2 + (j >> 1)][j & 1] + bb1[j],
                                            acc[2][2 + (j >> 1)][j & 1] + bb1[j],
                                            acc[3][2 + (j >> 1)][j & 1] + bb1[j]);
                    *(float4*)(slot + base0 + (size_t)j * TC) = v0;
                    *(float4*)(slot + base1 + (size_t)j * TC) = v1;
                }
            }
            __syncthreads();  // drains all waves' stores before signal
            if (tid == 0) {
                __threadfence();         // release
                atomicAdd(&done[k], 1u);
            }
        }
    }
}

// ---------------- host ----------------
extern "C" void kernel_launch(void* const* d_in, const int* in_sizes, int n_in,
                              void* d_out, int out_size, void* d_ws, size_t ws_size,
                              hipStream_t stream) {
    const float* x    = (const float*)d_in[0];
    const float* W_ih = (const float*)d_in[1];
    const float* W_hh = (const float*)d_in[2];
    const float* b_ih = (const float*)d_in[3];
    const float* b_hh = (const float*)d_in[4];
    float* out = (float*)d_out;

    char* ws = (char*)d_ws;
    float* Wt           = (float*)(ws);            // 200*512*4  = 409600
    float* bias         = (float*)(ws + 409600);   // 512*4      = 2048
    float* Whp          = (float*)(ws + 411648);   // 400*112*4  = 179200 -> 590848
    unsigned int* sync  = (unsigned int*)(ws + 590848);  // 64*4 = 256 -> 591104
    float* xgbuf        = (float*)(ws + 593920);   // ring buffers + 8KB slack

    size_t avail = (ws_size > 593920 + 8192) ? (ws_size - 593920 - 8192) : 0;
    int TC, NB;
    if (avail >= 2ull * B_SZ * 256 * GP * 4)      { TC = 256; NB = 2; }
    else if (avail >= 2ull * B_SZ * 128 * GP * 4) { TC = 128; NB = 2; }
    else                                          { TC = 128; NB = 1; }
    int nch = T_TOTAL / TC;

    prep_kernel<<<400, 256, 0, stream>>>(W_ih, W_hh, b_ih, b_hh, Wt, bias, Whp, sync);
    fused_kernel<<<NBLK, 512, 0, stream>>>(x, Wt, bias, Whp, xgbuf, out, sync,
                                           TC, NB, nch);
}